// Round 1
// baseline (796.171 us; speedup 1.0000x reference)
//
#include <hip/hip_runtime.h>
#include <hip/hip_bf16.h>
#include <math.h>

// Block_46643344834722: pre-norm attention block, B=512 D=2048 H=16 DH=128.
// Strategy: fp32 inputs staged to LDS as bf16, mfma_f32_16x16x32_bf16 GEMMs.

#define DDIM 2048
#define HHEADS 16
#define DHEAD 128
#define BROWS 512
#define LN_EPS 1e-5f

typedef __bf16 bf16x8_t __attribute__((ext_vector_type(8)));
typedef float f32x4_t __attribute__((ext_vector_type(4)));

// ---------------------------------------------------------------- LayerNorm
__global__ __launch_bounds__(256) void ln_kernel(const float* __restrict__ x,
                                                 const float* __restrict__ g,
                                                 const float* __restrict__ b,
                                                 float* __restrict__ out) {
    const int row = blockIdx.x;
    const int tid = threadIdx.x;
    const float4* x4 = (const float4*)(x + (size_t)row * DDIM);
    float4 a = x4[tid];
    float4 c = x4[tid + 256];
    float s  = a.x + a.y + a.z + a.w + c.x + c.y + c.z + c.w;
    float s2 = a.x*a.x + a.y*a.y + a.z*a.z + a.w*a.w
             + c.x*c.x + c.y*c.y + c.z*c.z + c.w*c.w;
    #pragma unroll
    for (int off = 32; off > 0; off >>= 1) {
        s  += __shfl_down(s, off);
        s2 += __shfl_down(s2, off);
    }
    __shared__ float ps[4], ps2[4];
    __shared__ float mean_s, rstd_s;
    const int lane = tid & 63, w = tid >> 6;
    if (lane == 0) { ps[w] = s; ps2[w] = s2; }
    __syncthreads();
    if (tid == 0) {
        float S  = ps[0] + ps[1] + ps[2] + ps[3];
        float S2 = ps2[0] + ps2[1] + ps2[2] + ps2[3];
        float m  = S * (1.0f / DDIM);
        float var = S2 * (1.0f / DDIM) - m * m;
        mean_s = m;
        rstd_s = rsqrtf(var + LN_EPS);
    }
    __syncthreads();
    const float m = mean_s, r = rstd_s;
    const float4* g4 = (const float4*)g;
    const float4* b4 = (const float4*)b;
    float4* o4 = (float4*)(out + (size_t)row * DDIM);
    float4 ga = g4[tid], gb = g4[tid + 256];
    float4 ba = b4[tid], bb = b4[tid + 256];
    float4 oa, ob;
    oa.x = (a.x - m) * r * ga.x + ba.x;
    oa.y = (a.y - m) * r * ga.y + ba.y;
    oa.z = (a.z - m) * r * ga.z + ba.z;
    oa.w = (a.w - m) * r * ga.w + ba.w;
    ob.x = (c.x - m) * r * gb.x + bb.x;
    ob.y = (c.y - m) * r * gb.y + bb.y;
    ob.z = (c.z - m) * r * gb.z + bb.z;
    ob.w = (c.w - m) * r * gb.w + bb.w;
    o4[tid] = oa;
    o4[tid + 256] = ob;
}

// ---------------------------------------------------------------- GEMM
// C[M,N] = A[M,K] @ B + bias (+ Res) (relu?).  64x64 tile, 256 thr = 4 waves,
// each wave a 32x32 quadrant (2x2 MFMA 16x16x32 bf16 tiles).
// qkv!=0: B is [H, K, 128] per-head stacked (cols c -> head c>>7, e c&127).
__global__ __launch_bounds__(256) void gemm_kernel(
    const float* __restrict__ A, int K,
    const float* __restrict__ B, int N, int qkv,
    const float* __restrict__ bias,
    const float* __restrict__ Res, int relu,
    float* __restrict__ C) {
    __shared__ __align__(16) __bf16 As[64][40];  // [m][k], +8 pad
    __shared__ __align__(16) __bf16 Bs[64][40];  // [n][k], +8 pad

    const int tid = threadIdx.x;
    const int bm = blockIdx.y, bn = blockIdx.x;

    const float* Bp;
    int ldb;
    if (qkv) {
        int c0 = bn * 64;
        Bp = B + (size_t)(c0 >> 7) * K * 128 + (c0 & 127);
        ldb = 128;
    } else {
        Bp = B + bn * 64;
        ldb = N;
    }

    // staging assignment
    const int ar = tid >> 2;          // A row 0..63
    const int ac = (tid & 3) << 3;    // A col 0,8,16,24
    const float* ag = A + (size_t)(bm * 64 + ar) * K + ac;
    const int bc = tid & 63;          // B col (n) 0..63
    const int br = (tid >> 6) << 3;   // B row (k) 0,8,16,24
    const float* bg = Bp + (size_t)br * ldb + bc;

    const int lane = tid & 63, w = tid >> 6;
    const int wm = (w >> 1) << 5, wn = (w & 1) << 5;
    const int mrow = lane & 15, quad = lane >> 4;

    f32x4_t acc[2][2] = {};

    union V8 { float4 f; __bf16 h[8]; };

    for (int k0 = 0; k0 < K; k0 += 32) {
        // --- stage A tile (fp32 -> bf16) ---
        float4 f0 = *(const float4*)(ag + k0);
        float4 f1 = *(const float4*)(ag + k0 + 4);
        V8 ua;
        ua.h[0] = (__bf16)f0.x; ua.h[1] = (__bf16)f0.y;
        ua.h[2] = (__bf16)f0.z; ua.h[3] = (__bf16)f0.w;
        ua.h[4] = (__bf16)f1.x; ua.h[5] = (__bf16)f1.y;
        ua.h[6] = (__bf16)f1.z; ua.h[7] = (__bf16)f1.w;
        *(float4*)&As[ar][ac] = ua.f;
        // --- stage B tile transposed ([n][k]) ---
        const float* bgk = bg + (size_t)k0 * ldb;
        float bv[8];
        #pragma unroll
        for (int u = 0; u < 8; u++) bv[u] = bgk[(size_t)u * ldb];
        V8 ub;
        #pragma unroll
        for (int u = 0; u < 8; u++) ub.h[u] = (__bf16)bv[u];
        *(float4*)&Bs[bc][br] = ub.f;
        __syncthreads();

        bf16x8_t a0 = *(const bf16x8_t*)&As[wm + mrow][quad * 8];
        bf16x8_t a1 = *(const bf16x8_t*)&As[wm + 16 + mrow][quad * 8];
        bf16x8_t b0 = *(const bf16x8_t*)&Bs[wn + mrow][quad * 8];
        bf16x8_t b1 = *(const bf16x8_t*)&Bs[wn + 16 + mrow][quad * 8];
        acc[0][0] = __builtin_amdgcn_mfma_f32_16x16x32_bf16(a0, b0, acc[0][0], 0, 0, 0);
        acc[0][1] = __builtin_amdgcn_mfma_f32_16x16x32_bf16(a0, b1, acc[0][1], 0, 0, 0);
        acc[1][0] = __builtin_amdgcn_mfma_f32_16x16x32_bf16(a1, b0, acc[1][0], 0, 0, 0);
        acc[1][1] = __builtin_amdgcn_mfma_f32_16x16x32_bf16(a1, b1, acc[1][1], 0, 0, 0);
        __syncthreads();
    }

    // --- epilogue: C/D layout col=lane&15, row=(lane>>4)*4+reg ---
    #pragma unroll
    for (int i = 0; i < 2; i++) {
        #pragma unroll
        for (int j = 0; j < 2; j++) {
            const int col = bn * 64 + wn + j * 16 + mrow;
            #pragma unroll
            for (int r = 0; r < 4; r++) {
                const int row = bm * 64 + wm + i * 16 + quad * 4 + r;
                float val = acc[i][j][r] + bias[col];
                if (Res) val += Res[(size_t)row * N + col];
                if (relu) val = fmaxf(val, 0.0f);
                C[(size_t)row * N + col] = val;
            }
        }
    }
}

// ---------------------------------------------------------------- Attention
// Per (b,h): o_i = sum_j softmax_j(q_i*k_j/sqrt(DH)) * v_j.
// Exp args bounded (|q*k|/11.3 < ~1) -> skip max subtraction (shift-invariant).
__global__ __launch_bounds__(128) void attn_kernel(const float* __restrict__ q,
                                                   const float* __restrict__ k,
                                                   const float* __restrict__ v,
                                                   float* __restrict__ o) {
    const int bh = blockIdx.x;  // b*H + h
    const size_t base = (size_t)(bh >> 4) * DDIM + (size_t)(bh & 15) * DHEAD;
    const int tid = threadIdx.x;
    __shared__ float ks[DHEAD], vs[DHEAD];
    ks[tid] = k[base + tid];
    vs[tid] = v[base + tid];
    __syncthreads();
    const float a = q[base + tid] * 0.08838834764831845f;  // 1/sqrt(128)
    float den = 0.0f, num = 0.0f;
    #pragma unroll 8
    for (int j = 0; j < DHEAD; j++) {
        float e = __expf(a * ks[j]);
        den += e;
        num += e * vs[j];
    }
    o[base + tid] = num / den;
}

// ---------------------------------------------------------------- launch
extern "C" void kernel_launch(void* const* d_in, const int* in_sizes, int n_in,
                              void* d_out, int out_size, void* d_ws, size_t ws_size,
                              hipStream_t stream) {
    const float* x   = (const float*)d_in[0];
    const float* Wq  = (const float*)d_in[1];
    const float* bq  = (const float*)d_in[2];
    const float* Wk  = (const float*)d_in[3];
    const float* bk  = (const float*)d_in[4];
    const float* Wv  = (const float*)d_in[5];
    const float* bv  = (const float*)d_in[6];
    const float* Wo  = (const float*)d_in[7];
    const float* bo  = (const float*)d_in[8];
    const float* W1  = (const float*)d_in[9];
    const float* b1  = (const float*)d_in[10];
    const float* W2  = (const float*)d_in[11];
    const float* b2  = (const float*)d_in[12];
    const float* g1  = (const float*)d_in[13];
    const float* be1 = (const float*)d_in[14];
    const float* g2  = (const float*)d_in[15];
    const float* be2 = (const float*)d_in[16];
    float* out = (float*)d_out;

    const size_t SZ = (size_t)BROWS * DDIM;  // 1,048,576 floats
    float* ws = (float*)d_ws;
    float* h   = ws + 0 * SZ;
    float* qb  = ws + 1 * SZ;
    float* kb  = ws + 2 * SZ;
    float* vb  = ws + 3 * SZ;
    float* ob  = ws + 4 * SZ;
    float* x1  = ws + 5 * SZ;
    float* h2  = ws + 6 * SZ;
    float* t   = ws + 7 * SZ;  // [512, 8192] = 4*SZ floats

    // h = LN(x)
    ln_kernel<<<BROWS, 256, 0, stream>>>(x, g1, be1, h);

    dim3 gqkv(DDIM / 64, BROWS / 64);  // (32, 8)
    gemm_kernel<<<gqkv, 256, 0, stream>>>(h, DDIM, Wq, DDIM, 1, bq, nullptr, 0, qb);
    gemm_kernel<<<gqkv, 256, 0, stream>>>(h, DDIM, Wk, DDIM, 1, bk, nullptr, 0, kb);
    gemm_kernel<<<gqkv, 256, 0, stream>>>(h, DDIM, Wv, DDIM, 1, bv, nullptr, 0, vb);

    attn_kernel<<<BROWS * HHEADS, 128, 0, stream>>>(qb, kb, vb, ob);

    // x1 = x + o @ Wo + bo
    gemm_kernel<<<gqkv, 256, 0, stream>>>(ob, DDIM, Wo, DDIM, 0, bo, x, 0, x1);

    // h2 = LN(x1)
    ln_kernel<<<BROWS, 256, 0, stream>>>(x1, g2, be2, h2);

    // t = relu(h2 @ W1 + b1)   [512, 8192]
    dim3 gffn1(4 * DDIM / 64, BROWS / 64);  // (128, 8)
    gemm_kernel<<<gffn1, 256, 0, stream>>>(h2, DDIM, W1, 4 * DDIM, 0, b1, nullptr, 1, t);

    // out = x1 + t @ W2 + b2
    dim3 gffn2(DDIM / 64, BROWS / 64);  // (32, 8)
    gemm_kernel<<<gffn2, 256, 0, stream>>>(t, 4 * DDIM, W2, DDIM, 0, b2, x1, 0, out);
}

// Round 2
// 470.559 us; speedup vs baseline: 1.6920x; 1.6920x over previous
//
#include <hip/hip_runtime.h>
#include <hip/hip_bf16.h>
#include <math.h>

// Block_46643344834722: pre-norm attention block, B=512 D=2048 H=16 DH=128.
// R2: m97-class GEMM — per-call weight transpose+convert to bf16 B^T[N,K],
// global_load_lds width-16 staging, bf16 activations, fused qkv GEMM.

#define DDIM 2048
#define HHEADS 16
#define DHEAD 128
#define BROWS 512
#define LN_EPS 1e-5f

typedef __bf16 bf16x8_t __attribute__((ext_vector_type(8)));
typedef float f32x4_t __attribute__((ext_vector_type(4)));

#define GLD16(gptr, lptr)                                                     \
    __builtin_amdgcn_global_load_lds(                                         \
        (const __attribute__((address_space(1))) void*)(gptr),                \
        (__attribute__((address_space(3))) void*)(lptr), 16, 0, 0)

// ---------------------------------------------------------------- LayerNorm
// x fp32 [512,2048] -> out bf16 [512,2048]. One block per row, 256 thr,
// 8 contiguous elems per thread.
__global__ __launch_bounds__(256) void ln_kernel(const float* __restrict__ x,
                                                 const float* __restrict__ g,
                                                 const float* __restrict__ b,
                                                 __bf16* __restrict__ out) {
    const int row = blockIdx.x;
    const int tid = threadIdx.x;
    const float4* x4 = (const float4*)(x + (size_t)row * DDIM);
    float4 a = x4[2 * tid];
    float4 c = x4[2 * tid + 1];
    float s  = a.x + a.y + a.z + a.w + c.x + c.y + c.z + c.w;
    float s2 = a.x*a.x + a.y*a.y + a.z*a.z + a.w*a.w
             + c.x*c.x + c.y*c.y + c.z*c.z + c.w*c.w;
    #pragma unroll
    for (int off = 32; off > 0; off >>= 1) {
        s  += __shfl_down(s, off);
        s2 += __shfl_down(s2, off);
    }
    __shared__ float ps[4], ps2[4];
    __shared__ float mean_s, rstd_s;
    const int lane = tid & 63, w = tid >> 6;
    if (lane == 0) { ps[w] = s; ps2[w] = s2; }
    __syncthreads();
    if (tid == 0) {
        float S  = ps[0] + ps[1] + ps[2] + ps[3];
        float S2 = ps2[0] + ps2[1] + ps2[2] + ps2[3];
        float m  = S * (1.0f / DDIM);
        float var = S2 * (1.0f / DDIM) - m * m;
        mean_s = m;
        rstd_s = rsqrtf(var + LN_EPS);
    }
    __syncthreads();
    const float m = mean_s, r = rstd_s;
    const float4* g4 = (const float4*)g;
    const float4* b4 = (const float4*)b;
    float4 ga = g4[2 * tid], gb = g4[2 * tid + 1];
    float4 ba = b4[2 * tid], bb = b4[2 * tid + 1];
    bf16x8_t o;
    o[0] = (__bf16)((a.x - m) * r * ga.x + ba.x);
    o[1] = (__bf16)((a.y - m) * r * ga.y + ba.y);
    o[2] = (__bf16)((a.z - m) * r * ga.z + ba.z);
    o[3] = (__bf16)((a.w - m) * r * ga.w + ba.w);
    o[4] = (__bf16)((c.x - m) * r * gb.x + bb.x);
    o[5] = (__bf16)((c.y - m) * r * gb.y + bb.y);
    o[6] = (__bf16)((c.z - m) * r * gb.z + bb.z);
    o[7] = (__bf16)((c.w - m) * r * gb.w + bb.w);
    *(bf16x8_t*)(out + (size_t)row * DDIM + tid * 8) = o;
}

// ---------------------------------------------------------------- Transpose
// src fp32 [R,C] (batched) -> dst bf16 [C,R] (batched, stride R*C).
__global__ __launch_bounds__(256) void transpose_kernel(
    const float* __restrict__ src, __bf16* __restrict__ dst, int R, int C) {
    __shared__ float tile[32][33];
    const size_t bofs = (size_t)blockIdx.z * R * C;
    src += bofs;
    dst += bofs;
    const int c0 = blockIdx.x * 32, r0 = blockIdx.y * 32;
    const int tx = threadIdx.x & 31, ty = threadIdx.x >> 5;  // 32 x 8
    #pragma unroll
    for (int i = 0; i < 32; i += 8)
        tile[ty + i][tx] = src[(size_t)(r0 + ty + i) * C + c0 + tx];
    __syncthreads();
    #pragma unroll
    for (int i = 0; i < 32; i += 8)
        dst[(size_t)(c0 + ty + i) * R + r0 + tx] = (__bf16)tile[tx][ty + i];
}

// ---------------------------------------------------------------- fused bias
__global__ __launch_bounds__(256) void fuse_bias_kernel(
    const float* __restrict__ bq, const float* __restrict__ bk,
    const float* __restrict__ bv, float* __restrict__ fb) {
    const int i = blockIdx.x * 256 + threadIdx.x;  // 0..6143
    float v;
    if (i < 2048) v = bq[i];
    else if (i < 4096) v = bk[i - 2048];
    else v = bv[i - 4096];
    fb[i] = v;
}

// ---------------------------------------------------------------- GEMM (B^T)
// C[M,N] = A[M,K] @ Bt[N,K]^T + bias (+Res) (relu?).  bf16 in, fp32 acc.
// TMxTN tile, 256 thr = 4 waves in 2x2; global_load_lds 16B staging into
// unpadded As[TM][32] / Bs[TN][32] bf16.
template <int TM, int TN, int OUT_BF16, int RELU, int RES>
__global__ __launch_bounds__(256) void gemm_bt(
    const __bf16* __restrict__ A, int K,
    const __bf16* __restrict__ Bt,
    const float* __restrict__ bias,
    const float* __restrict__ Res,
    void* __restrict__ Cout, int N) {
    __shared__ __align__(16) __bf16 As[TM * 32];
    __shared__ __align__(16) __bf16 Bs[TN * 32];

    const int tid = threadIdx.x;
    const int w = tid >> 6, lane = tid & 63;
    const int m0 = blockIdx.y * TM, n0 = blockIdx.x * TN;

    constexpr int NA = TM / 16;          // A staging instructions (1 KB each)
    constexpr int NT = (TM + TN) / 16;   // total staging instructions
    constexpr int NI = NT / 4;           // per wave

    // per-lane source row/col within a 16-row chunk
    const int sub_r = lane >> 2;
    const int sub_k = (lane & 3) * 8;

    const __bf16* srcs[NI];
    __bf16* dsts[NI];
    #pragma unroll
    for (int i = 0; i < NI; i++) {
        const int t = w + 4 * i;
        if (t < NA) {
            srcs[i] = A + (size_t)(m0 + t * 16 + sub_r) * K + sub_k;
            dsts[i] = As + t * 512;
        } else {
            const int tb = t - NA;
            srcs[i] = Bt + (size_t)(n0 + tb * 16 + sub_r) * K + sub_k;
            dsts[i] = Bs + tb * 512;
        }
    }

    constexpr int MI = TM / 32;  // 16-tiles per wave (m)
    constexpr int NJ = TN / 32;  // 16-tiles per wave (n)
    const int wm = (w >> 1) * (TM / 2), wn = (w & 1) * (TN / 2);
    const int fm = lane & 15, quad = lane >> 4;

    f32x4_t acc[MI][NJ] = {};

    for (int k0 = 0; k0 < K; k0 += 32) {
        #pragma unroll
        for (int i = 0; i < NI; i++) GLD16(srcs[i] + k0, dsts[i]);
        __syncthreads();

        bf16x8_t a[MI], b[NJ];
        #pragma unroll
        for (int i = 0; i < MI; i++)
            a[i] = *(const bf16x8_t*)&As[(wm + i * 16 + fm) * 32 + quad * 8];
        #pragma unroll
        for (int j = 0; j < NJ; j++)
            b[j] = *(const bf16x8_t*)&Bs[(wn + j * 16 + fm) * 32 + quad * 8];
        #pragma unroll
        for (int i = 0; i < MI; i++)
            #pragma unroll
            for (int j = 0; j < NJ; j++)
                acc[i][j] = __builtin_amdgcn_mfma_f32_16x16x32_bf16(
                    a[i], b[j], acc[i][j], 0, 0, 0);
        __syncthreads();
    }

    // epilogue: C/D layout col=lane&15, row=quad*4+reg
    #pragma unroll
    for (int i = 0; i < MI; i++) {
        #pragma unroll
        for (int j = 0; j < NJ; j++) {
            const int col = n0 + wn + j * 16 + fm;
            const float bcol = bias[col];
            #pragma unroll
            for (int r = 0; r < 4; r++) {
                const int row = m0 + wm + i * 16 + quad * 4 + r;
                float val = acc[i][j][r] + bcol;
                if (RES) val += Res[(size_t)row * N + col];
                if (RELU) val = fmaxf(val, 0.0f);
                if (OUT_BF16)
                    ((__bf16*)Cout)[(size_t)row * N + col] = (__bf16)val;
                else
                    ((float*)Cout)[(size_t)row * N + col] = val;
            }
        }
    }
}

// ---------------------------------------------------------------- Attention
// qkv bf16 [512, 6144] (q|k|v per row, each [H,DH]); o bf16 [512, 2048].
// o_i = sum_j softmax_j(q_i*k_j/sqrt(DH)) * v_j   (outer-product softmax)
__global__ __launch_bounds__(128) void attn_kernel(
    const __bf16* __restrict__ qkv, __bf16* __restrict__ o) {
    const int bh = blockIdx.x;  // b*H + h
    const int b = bh >> 4, h = bh & 15;
    const size_t base = (size_t)b * (3 * DDIM) + h * DHEAD;
    const int tid = threadIdx.x;
    __shared__ float ks[DHEAD], vs[DHEAD];
    ks[tid] = (float)qkv[base + DDIM + tid];
    vs[tid] = (float)qkv[base + 2 * DDIM + tid];
    __syncthreads();
    const float a = (float)qkv[base + tid] * 0.08838834764831845f;  // /sqrt(128)
    float den = 0.0f, num = 0.0f;
    #pragma unroll 8
    for (int j = 0; j < DHEAD; j++) {
        float e = __expf(a * ks[j]);
        den += e;
        num += e * vs[j];
    }
    o[(size_t)b * DDIM + h * DHEAD + tid] = (__bf16)(num / den);
}

// ---------------------------------------------------------------- launch
extern "C" void kernel_launch(void* const* d_in, const int* in_sizes, int n_in,
                              void* d_out, int out_size, void* d_ws, size_t ws_size,
                              hipStream_t stream) {
    const float* x   = (const float*)d_in[0];
    const float* Wq  = (const float*)d_in[1];
    const float* bq  = (const float*)d_in[2];
    const float* Wk  = (const float*)d_in[3];
    const float* bk  = (const float*)d_in[4];
    const float* Wv  = (const float*)d_in[5];
    const float* bv  = (const float*)d_in[6];
    const float* Wo  = (const float*)d_in[7];
    const float* bo  = (const float*)d_in[8];
    const float* W1  = (const float*)d_in[9];
    const float* b1  = (const float*)d_in[10];
    const float* W2  = (const float*)d_in[11];
    const float* b2  = (const float*)d_in[12];
    const float* g1  = (const float*)d_in[13];
    const float* be1 = (const float*)d_in[14];
    const float* g2  = (const float*)d_in[15];
    const float* be2 = (const float*)d_in[16];
    float* out = (float*)d_out;

    // ---- workspace layout (bytes), lifetime-overlapped ----
    char* base = (char*)d_ws;
    float*  fb     = (float*)(base + 0);              //   24,576 B
    __bf16* bt_qkv = (__bf16*)(base + 32768);         // 25,165,824 B  [6144,2048]
    char*   slotA  = base + 32768 + 25165824;         // 33,554,432 B
    char*   slotB  = slotA + 33554432;                // 33,554,432 B
    // activations in dead regions:
    __bf16* h   = (__bf16*)(slotB + 0);               // bf16 [512,2048] (pre-W1t)
    __bf16* qkv = (__bf16*)(slotB + 2097152);         // bf16 [512,6144]
    __bf16* ob  = (__bf16*)(slotB + 8388608);         // bf16 [512,2048]
    float*  x1  = (float*)((char*)bt_qkv + 0);        // fp32 [512,2048] (post-qkv)
    __bf16* h2  = (__bf16*)((char*)bt_qkv + 4194304); // bf16 [512,2048]
    __bf16* t   = (__bf16*)((char*)bt_qkv + 6291456); // bf16 [512,8192]
    __bf16* Wot = (__bf16*)slotA;                     // [2048,2048]
    __bf16* W1t = (__bf16*)slotB;                     // [8192,2048]
    __bf16* W2t = (__bf16*)slotA;                     // [2048,8192]

    fuse_bias_kernel<<<24, 256, 0, stream>>>(bq, bk, bv, fb);

    // transposed bf16 weights: B^T[N,K]
    transpose_kernel<<<dim3(4, 64, 16), 256, 0, stream>>>(Wq, bt_qkv, DDIM, DHEAD);
    transpose_kernel<<<dim3(4, 64, 16), 256, 0, stream>>>(Wk, bt_qkv + 2048 * 2048, DDIM, DHEAD);
    transpose_kernel<<<dim3(4, 64, 16), 256, 0, stream>>>(Wv, bt_qkv + 2 * 2048 * 2048, DDIM, DHEAD);
    transpose_kernel<<<dim3(64, 64, 1), 256, 0, stream>>>(Wo, Wot, DDIM, DDIM);

    // h = LN(x)
    ln_kernel<<<BROWS, 256, 0, stream>>>(x, g1, be1, h);

    // qkv = h @ [Wq|Wk|Wv] + [bq|bk|bv]   -> bf16 [512,6144]
    gemm_bt<64, 128, 1, 0, 0><<<dim3(48, 8), 256, 0, stream>>>(
        h, DDIM, bt_qkv, fb, nullptr, qkv, 3 * DDIM);

    attn_kernel<<<BROWS * HHEADS, 128, 0, stream>>>(qkv, ob);

    // x1 = x + ob @ Wo + bo
    gemm_bt<64, 64, 0, 0, 1><<<dim3(32, 8), 256, 0, stream>>>(
        ob, DDIM, Wot, bo, x, x1, DDIM);

    // late transposes into now-dead regions
    transpose_kernel<<<dim3(256, 64, 1), 256, 0, stream>>>(W1, W1t, DDIM, 4 * DDIM);
    transpose_kernel<<<dim3(64, 256, 1), 256, 0, stream>>>(W2, W2t, 4 * DDIM, DDIM);

    // h2 = LN(x1)
    ln_kernel<<<BROWS, 256, 0, stream>>>(x1, g2, be2, h2);

    // t = relu(h2 @ W1 + b1)  -> bf16 [512,8192]
    gemm_bt<64, 128, 1, 1, 0><<<dim3(64, 8), 256, 0, stream>>>(
        h2, DDIM, W1t, b1, nullptr, t, 4 * DDIM);

    // out = x1 + t @ W2 + b2  -> fp32 [512,2048]
    gemm_bt<64, 64, 0, 0, 1><<<dim3(32, 8), 256, 0, stream>>>(
        t, 4 * DDIM, W2t, b2, x1, out, DDIM);
}

// Round 3
// 404.279 us; speedup vs baseline: 1.9694x; 1.1639x over previous
//
#include <hip/hip_runtime.h>
#include <hip/hip_bf16.h>
#include <math.h>

// Block_46643344834722: pre-norm attention block, B=512 D=2048 H=16 DH=128.
// R3: 4-stage circular LDS pipeline in the GEMM — never wait vmcnt(0);
// raw s_barrier via asm so __syncthreads' full drain is avoided.

#define DDIM 2048
#define HHEADS 16
#define DHEAD 128
#define BROWS 512
#define LN_EPS 1e-5f

typedef __bf16 bf16x8_t __attribute__((ext_vector_type(8)));
typedef float f32x4_t __attribute__((ext_vector_type(4)));

#define GLD16(gptr, lptr)                                                     \
    __builtin_amdgcn_global_load_lds(                                         \
        (const __attribute__((address_space(1))) void*)(gptr),                \
        (__attribute__((address_space(3))) void*)(lptr), 16, 0, 0)

// ---------------------------------------------------------------- LayerNorm
__global__ __launch_bounds__(256) void ln_kernel(const float* __restrict__ x,
                                                 const float* __restrict__ g,
                                                 const float* __restrict__ b,
                                                 __bf16* __restrict__ out) {
    const int row = blockIdx.x;
    const int tid = threadIdx.x;
    const float4* x4 = (const float4*)(x + (size_t)row * DDIM);
    float4 a = x4[2 * tid];
    float4 c = x4[2 * tid + 1];
    float s  = a.x + a.y + a.z + a.w + c.x + c.y + c.z + c.w;
    float s2 = a.x*a.x + a.y*a.y + a.z*a.z + a.w*a.w
             + c.x*c.x + c.y*c.y + c.z*c.z + c.w*c.w;
    #pragma unroll
    for (int off = 32; off > 0; off >>= 1) {
        s  += __shfl_down(s, off);
        s2 += __shfl_down(s2, off);
    }
    __shared__ float ps[4], ps2[4];
    __shared__ float mean_s, rstd_s;
    const int lane = tid & 63, w = tid >> 6;
    if (lane == 0) { ps[w] = s; ps2[w] = s2; }
    __syncthreads();
    if (tid == 0) {
        float S  = ps[0] + ps[1] + ps[2] + ps[3];
        float S2 = ps2[0] + ps2[1] + ps2[2] + ps2[3];
        float m  = S * (1.0f / DDIM);
        float var = S2 * (1.0f / DDIM) - m * m;
        mean_s = m;
        rstd_s = rsqrtf(var + LN_EPS);
    }
    __syncthreads();
    const float m = mean_s, r = rstd_s;
    const float4* g4 = (const float4*)g;
    const float4* b4 = (const float4*)b;
    float4 ga = g4[2 * tid], gb = g4[2 * tid + 1];
    float4 ba = b4[2 * tid], bb = b4[2 * tid + 1];
    bf16x8_t o;
    o[0] = (__bf16)((a.x - m) * r * ga.x + ba.x);
    o[1] = (__bf16)((a.y - m) * r * ga.y + ba.y);
    o[2] = (__bf16)((a.z - m) * r * ga.z + ba.z);
    o[3] = (__bf16)((a.w - m) * r * ga.w + ba.w);
    o[4] = (__bf16)((c.x - m) * r * gb.x + bb.x);
    o[5] = (__bf16)((c.y - m) * r * gb.y + bb.y);
    o[6] = (__bf16)((c.z - m) * r * gb.z + bb.z);
    o[7] = (__bf16)((c.w - m) * r * gb.w + bb.w);
    *(bf16x8_t*)(out + (size_t)row * DDIM + tid * 8) = o;
}

// ---------------------------------------------------------------- Transpose
// src fp32 [R,C] (batched) -> dst bf16 [C,R] (batched, stride R*C).
__global__ __launch_bounds__(256) void transpose_kernel(
    const float* __restrict__ src, __bf16* __restrict__ dst, int R, int C) {
    __shared__ float tile[32][33];
    const size_t bofs = (size_t)blockIdx.z * R * C;
    src += bofs;
    dst += bofs;
    const int c0 = blockIdx.x * 32, r0 = blockIdx.y * 32;
    const int tx = threadIdx.x & 31, ty = threadIdx.x >> 5;  // 32 x 8
    #pragma unroll
    for (int i = 0; i < 32; i += 8)
        tile[ty + i][tx] = src[(size_t)(r0 + ty + i) * C + c0 + tx];
    __syncthreads();
    #pragma unroll
    for (int i = 0; i < 32; i += 8)
        dst[(size_t)(c0 + ty + i) * R + r0 + tx] = (__bf16)tile[tx][ty + i];
}

// ---------------------------------------------------------------- fused bias
__global__ __launch_bounds__(256) void fuse_bias_kernel(
    const float* __restrict__ bq, const float* __restrict__ bk,
    const float* __restrict__ bv, float* __restrict__ fb) {
    const int i = blockIdx.x * 256 + threadIdx.x;  // 0..6143
    float v;
    if (i < 2048) v = bq[i];
    else if (i < 4096) v = bk[i - 2048];
    else v = bv[i - 4096];
    fb[i] = v;
}

// ---------------------------------------------------------------- GEMM (B^T)
// C[M,N] = A[M,K] @ Bt[N,K]^T + bias (+Res) (relu?).  bf16 in, fp32 acc.
// 4-stage circular LDS pipeline: wait vmcnt((D-1)*NI), raw s_barrier,
// compute stage k, lgkm-barrier, refill slot with stage k+4.
template <int TM, int TN, int OUT_BF16, int RELU, int RES>
__global__ __launch_bounds__(256) void gemm_bt(
    const __bf16* __restrict__ A, int K,
    const __bf16* __restrict__ Bt,
    const float* __restrict__ bias,
    const float* __restrict__ Res,
    void* __restrict__ Cout, int N) {
    constexpr int DEPTH = 4;
    constexpr int STG = (TM + TN) * 32;  // bf16 elems per stage
    __shared__ __align__(16) __bf16 smem[DEPTH * STG];

    const int tid = threadIdx.x;
    const int w = tid >> 6, lane = tid & 63;
    const int m0 = blockIdx.y * TM, n0 = blockIdx.x * TN;

    constexpr int NA = TM / 16;          // A staging chunks (1 KB each)
    constexpr int NT = (TM + TN) / 16;   // total chunks
    constexpr int NI = NT / 4;           // chunks per wave

    // lane's 16B within a 16-row x 32-col bf16 chunk
    const int sub_r = lane >> 2;
    const int sub_k = (lane & 3) * 8;

    const __bf16* srcs[NI];
    int toff[NI];  // wave-uniform LDS chunk offsets (bf16 elems)
    #pragma unroll
    for (int i = 0; i < NI; i++) {
        const int t = w + 4 * i;
        toff[i] = t * 512;
        if (t < NA)
            srcs[i] = A + (size_t)(m0 + t * 16 + sub_r) * K + sub_k;
        else
            srcs[i] = Bt + (size_t)(n0 + (t - NA) * 16 + sub_r) * K + sub_k;
    }

    constexpr int MI = TM / 32;  // 16-tiles per wave (m)
    constexpr int NJ = TN / 32;  // 16-tiles per wave (n)
    const int wm = (w >> 1) * (TM / 2), wn = (w & 1) * (TN / 2);
    const int fm = lane & 15, quad = lane >> 4;

    f32x4_t acc[MI][NJ] = {};

    const int NK = K / 32;

    // prologue: fill all DEPTH stages
    #pragma unroll
    for (int d = 0; d < DEPTH; d++)
        #pragma unroll
        for (int i = 0; i < NI; i++)
            GLD16(srcs[i] + d * 32, smem + d * STG + toff[i]);

    for (int ks = 0; ks < NK; ks++) {
        const __bf16* st = smem + (ks & (DEPTH - 1)) * STG;
        // oldest stage (ks) complete: <= (DEPTH-1)*NI loads outstanding
        asm volatile("s_waitcnt vmcnt(%0)\n\ts_barrier"
                     :: "i"((DEPTH - 1) * NI) : "memory");

        bf16x8_t a[MI], b[NJ];
        #pragma unroll
        for (int i = 0; i < MI; i++)
            a[i] = *(const bf16x8_t*)&st[(wm + i * 16 + fm) * 32 + quad * 8];
        #pragma unroll
        for (int j = 0; j < NJ; j++)
            b[j] = *(const bf16x8_t*)&st[TM * 32 + (wn + j * 16 + fm) * 32 + quad * 8];
        #pragma unroll
        for (int i = 0; i < MI; i++)
            #pragma unroll
            for (int j = 0; j < NJ; j++)
                acc[i][j] = __builtin_amdgcn_mfma_f32_16x16x32_bf16(
                    a[i], b[j], acc[i][j], 0, 0, 0);

        // all waves done reading this slot before refilling it
        asm volatile("s_waitcnt lgkmcnt(0)\n\ts_barrier" ::: "memory");
        if (ks + DEPTH < NK) {
            __bf16* dst = smem + (ks & (DEPTH - 1)) * STG;
            #pragma unroll
            for (int i = 0; i < NI; i++)
                GLD16(srcs[i] + (ks + DEPTH) * 32, dst + toff[i]);
        }
    }

    // epilogue: C/D layout col=lane&15, row=quad*4+reg
    #pragma unroll
    for (int i = 0; i < MI; i++) {
        #pragma unroll
        for (int j = 0; j < NJ; j++) {
            const int col = n0 + wn + j * 16 + fm;
            const float bcol = bias[col];
            #pragma unroll
            for (int r = 0; r < 4; r++) {
                const int row = m0 + wm + i * 16 + quad * 4 + r;
                float val = acc[i][j][r] + bcol;
                if (RES) val += Res[(size_t)row * N + col];
                if (RELU) val = fmaxf(val, 0.0f);
                if (OUT_BF16)
                    ((__bf16*)Cout)[(size_t)row * N + col] = (__bf16)val;
                else
                    ((float*)Cout)[(size_t)row * N + col] = val;
            }
        }
    }
}

// ---------------------------------------------------------------- Attention
// qkv bf16 [512, 6144] (q|k|v per row, each [H,DH]); o bf16 [512, 2048].
__global__ __launch_bounds__(128) void attn_kernel(
    const __bf16* __restrict__ qkv, __bf16* __restrict__ o) {
    const int bh = blockIdx.x;  // b*H + h
    const int b = bh >> 4, h = bh & 15;
    const size_t base = (size_t)b * (3 * DDIM) + h * DHEAD;
    const int tid = threadIdx.x;
    __shared__ float ks[DHEAD], vs[DHEAD];
    ks[tid] = (float)qkv[base + DDIM + tid];
    vs[tid] = (float)qkv[base + 2 * DDIM + tid];
    __syncthreads();
    const float a = (float)qkv[base + tid] * 0.08838834764831845f;  // /sqrt(128)
    float den = 0.0f, num = 0.0f;
    #pragma unroll 8
    for (int j = 0; j < DHEAD; j++) {
        float e = __expf(a * ks[j]);
        den += e;
        num += e * vs[j];
    }
    o[(size_t)b * DDIM + h * DHEAD + tid] = (__bf16)(num / den);
}

// ---------------------------------------------------------------- launch
extern "C" void kernel_launch(void* const* d_in, const int* in_sizes, int n_in,
                              void* d_out, int out_size, void* d_ws, size_t ws_size,
                              hipStream_t stream) {
    const float* x   = (const float*)d_in[0];
    const float* Wq  = (const float*)d_in[1];
    const float* bq  = (const float*)d_in[2];
    const float* Wk  = (const float*)d_in[3];
    const float* bk  = (const float*)d_in[4];
    const float* Wv  = (const float*)d_in[5];
    const float* bv  = (const float*)d_in[6];
    const float* Wo  = (const float*)d_in[7];
    const float* bo  = (const float*)d_in[8];
    const float* W1  = (const float*)d_in[9];
    const float* b1  = (const float*)d_in[10];
    const float* W2  = (const float*)d_in[11];
    const float* b2  = (const float*)d_in[12];
    const float* g1  = (const float*)d_in[13];
    const float* be1 = (const float*)d_in[14];
    const float* g2  = (const float*)d_in[15];
    const float* be2 = (const float*)d_in[16];
    float* out = (float*)d_out;

    // ---- workspace layout (bytes), lifetime-overlapped ----
    char* base = (char*)d_ws;
    float*  fb     = (float*)(base + 0);              //   24,576 B
    __bf16* bt_qkv = (__bf16*)(base + 32768);         // 25,165,824 B  [6144,2048]
    char*   slotA  = base + 32768 + 25165824;         // 33,554,432 B
    char*   slotB  = slotA + 33554432;                // 33,554,432 B
    // activations in dead regions:
    __bf16* h   = (__bf16*)(slotB + 0);               // bf16 [512,2048] (pre-W1t)
    __bf16* qkv = (__bf16*)(slotB + 2097152);         // bf16 [512,6144]
    __bf16* ob  = (__bf16*)(slotB + 8388608);         // bf16 [512,2048]
    float*  x1  = (float*)((char*)bt_qkv + 0);        // fp32 [512,2048] (post-qkv)
    __bf16* h2  = (__bf16*)((char*)bt_qkv + 4194304); // bf16 [512,2048]
    __bf16* t   = (__bf16*)((char*)bt_qkv + 6291456); // bf16 [512,8192]
    __bf16* Wot = (__bf16*)slotA;                     // [2048,2048]
    __bf16* W1t = (__bf16*)slotB;                     // [8192,2048]
    __bf16* W2t = (__bf16*)slotA;                     // [2048,8192]

    fuse_bias_kernel<<<24, 256, 0, stream>>>(bq, bk, bv, fb);

    // transposed bf16 weights: B^T[N,K]
    transpose_kernel<<<dim3(4, 64, 16), 256, 0, stream>>>(Wq, bt_qkv, DDIM, DHEAD);
    transpose_kernel<<<dim3(4, 64, 16), 256, 0, stream>>>(Wk, bt_qkv + 2048 * 2048, DDIM, DHEAD);
    transpose_kernel<<<dim3(4, 64, 16), 256, 0, stream>>>(Wv, bt_qkv + 2 * 2048 * 2048, DDIM, DHEAD);
    transpose_kernel<<<dim3(64, 64, 1), 256, 0, stream>>>(Wo, Wot, DDIM, DDIM);

    // h = LN(x)
    ln_kernel<<<BROWS, 256, 0, stream>>>(x, g1, be1, h);

    // qkv = h @ [Wq|Wk|Wv] + [bq|bk|bv]   -> bf16 [512,6144]
    gemm_bt<64, 128, 1, 0, 0><<<dim3(48, 8), 256, 0, stream>>>(
        h, DDIM, bt_qkv, fb, nullptr, qkv, 3 * DDIM);

    attn_kernel<<<BROWS * HHEADS, 128, 0, stream>>>(qkv, ob);

    // x1 = x + ob @ Wo + bo
    gemm_bt<64, 64, 0, 0, 1><<<dim3(32, 8), 256, 0, stream>>>(
        ob, DDIM, Wot, bo, x, x1, DDIM);

    // late transposes into now-dead regions
    transpose_kernel<<<dim3(256, 64, 1), 256, 0, stream>>>(W1, W1t, DDIM, 4 * DDIM);
    transpose_kernel<<<dim3(64, 256, 1), 256, 0, stream>>>(W2, W2t, 4 * DDIM, DDIM);

    // h2 = LN(x1)
    ln_kernel<<<BROWS, 256, 0, stream>>>(x1, g2, be2, h2);

    // t = relu(h2 @ W1 + b1)  -> bf16 [512,8192]
    gemm_bt<64, 128, 1, 1, 0><<<dim3(64, 8), 256, 0, stream>>>(
        h2, DDIM, W1t, b1, nullptr, t, 4 * DDIM);

    // out = x1 + t @ W2 + b2  -> fp32 [512,2048]
    gemm_bt<64, 64, 0, 0, 1><<<dim3(32, 8), 256, 0, stream>>>(
        t, 4 * DDIM, W2t, b2, x1, out, DDIM);
}